// Round 7
// baseline (311.309 us; speedup 1.0000x reference)
//
#include <hip/hip_runtime.h>
#include <hip/hip_bf16.h>

// PLE multi-task model, fused bf16-MFMA implementation.
// Round 7: wave-private expert pipelines. R2/R6 proved occupancy is NOT the
// lever (2->3 blocks/CU = 0 gain); the 7-barrier lockstep chain is. Now:
// wave w (0-5) runs expert w's L1->L2->L3 privately (h1/h2 via wave-private
// LDS slabs, in-wave lgkmcnt ordering only); waves 6-7 do the gate GEMM.
// Barriers: 7 -> 4. Gate softmax computed inline (redundantly) in mixing.
// Expert order: e0,e1 = task1; e2,e3 = task2; e4,e5 = shared.

#define MT 32          // tokens per block
#define NT1 25         // layer-1 N-tiles (24 expert + 1 gate)

typedef __bf16 bf16x8 __attribute__((ext_vector_type(8)));
typedef float f32x4 __attribute__((ext_vector_type(4)));

__device__ __forceinline__ unsigned short f2bf(float f) {
    unsigned u = __builtin_bit_cast(unsigned, f);
    return (unsigned short)((u + 0x7FFFu + ((u >> 16) & 1u)) >> 16);
}
__device__ __forceinline__ unsigned pk(float a, float b) {
    return (unsigned)f2bf(a) | ((unsigned)f2bf(b) << 16);
}

// ---------------- weight packing (single kernel, unchanged layout) ----------------
// wf1[nt=25][ks=16][lane=64][j=8]: W1cat[k = ks*32+(lane>>4)*8+j][col = nt*16+(lane&15)]
// cols 0-383 = experts (e = col/64), 384-387 = g1_W, 388-391 = g2_W.
// wf2[e][nt=2][ks=2][lane][8], wf3[e][nt=2][lane][8], packed biases b1c/b2c/b3c
__global__ void pack_all(const float* __restrict__ sh_W1, const float* __restrict__ t1_W1,
                         const float* __restrict__ t2_W1, const float* __restrict__ g1_W,
                         const float* __restrict__ g2_W,
                         const float* __restrict__ sh_W2, const float* __restrict__ t1_W2,
                         const float* __restrict__ t2_W2,
                         const float* __restrict__ sh_W3, const float* __restrict__ t1_W3,
                         const float* __restrict__ t2_W3,
                         const float* __restrict__ sh_b1, const float* __restrict__ t1_b1,
                         const float* __restrict__ t2_b1,
                         const float* __restrict__ sh_b2, const float* __restrict__ t1_b2,
                         const float* __restrict__ t2_b2,
                         const float* __restrict__ sh_b3, const float* __restrict__ t1_b3,
                         const float* __restrict__ t2_b3,
                         const float* __restrict__ g1_b, const float* __restrict__ g2_b,
                         unsigned short* __restrict__ wf1, unsigned short* __restrict__ wf2,
                         unsigned short* __restrict__ wf3,
                         float* __restrict__ b1c, float* __restrict__ b2c, float* __restrict__ b3c) {
    int p0 = blockIdx.x * blockDim.x + threadIdx.x;
    if (p0 < 204800) {                     // wf1: 25*16*64*8
        int p = p0;
        int j = p & 7, lane = (p >> 3) & 63, ks = (p >> 9) & 15, nt = p >> 13;
        int col = nt * 16 + (lane & 15);
        int k = ks * 32 + (lane >> 4) * 8 + j;
        float v = 0.f;
        if (col < 384) {
            int e = col >> 6, ci = col & 63;
            const float* W = (e < 2) ? t1_W1 : (e < 4) ? t2_W1 : sh_W1;
            v = W[((size_t)(e & 1) * 512 + k) * 64 + ci];
        } else if (col < 388) {
            v = g1_W[k * 4 + (col - 384)];
        } else if (col < 392) {
            v = g2_W[k * 4 + (col - 388)];
        }
        wf1[p] = f2bf(v);
        return;
    }
    int p = p0 - 204800;
    if (p < 12288) {                       // wf2: 6*2*2*64*8
        int j = p & 7, lane = (p >> 3) & 63, ks = (p >> 9) & 1, nt = (p >> 10) & 1, e = p >> 11;
        int col = nt * 16 + (lane & 15);
        int k = ks * 32 + (lane >> 4) * 8 + j;
        const float* W = (e < 2) ? t1_W2 : (e < 4) ? t2_W2 : sh_W2;
        wf2[p] = f2bf(W[((size_t)(e & 1) * 64 + k) * 32 + col]);
    } else if (p < 18432) {                // wf3: 6*2*64*8
        int q = p - 12288;
        int j = q & 7, lane = (q >> 3) & 63, nt = (q >> 9) & 1, e = q >> 10;
        int col = nt * 16 + (lane & 15);
        int k = (lane >> 4) * 8 + j;
        const float* W = (e < 2) ? t1_W3 : (e < 4) ? t2_W3 : sh_W3;
        wf3[q] = f2bf(W[((size_t)(e & 1) * 32 + k) * 32 + col]);
    } else if (p < 18432 + 392) {          // b1c[392]: expert b1 (384) + g1_b(4) + g2_b(4)
        int t = p - 18432;
        float v;
        if (t < 384) {
            int e = t >> 6, ci = t & 63;
            const float* bb = (e < 2) ? t1_b1 : (e < 4) ? t2_b1 : sh_b1;
            v = bb[(e & 1) * 64 + ci];
        } else if (t < 388) v = g1_b[t - 384];
        else v = g2_b[t - 388];
        b1c[t] = v;
    } else if (p < 18824 + 192) {          // b2c[192]
        int t = p - 18824;
        int e = t >> 5, ci = t & 31;
        const float* bb = (e < 2) ? t1_b2 : (e < 4) ? t2_b2 : sh_b2;
        b2c[t] = bb[(e & 1) * 32 + ci];
    } else if (p < 19016 + 192) {          // b3c[192]
        int t = p - 19016;
        int e = t >> 5, ci = t & 31;
        const float* bb = (e < 2) ? t1_b3 : (e < 4) ? t2_b3 : sh_b3;
        b3c[t] = bb[(e & 1) * 32 + ci];
    }
}

// ---------------- fused main kernel ----------------
// LDS map (bytes), MT=32, total 77,312 -> 2 blocks/CU:
//   [0, 33280)   xlds [32][520] bf16 (P1 write, P2 K-loop read by all waves)
//                after barrier2 aliased: g1l f32 [32][33] @0, g2l @4224,
//                th1 f32 [32][66] @8448, th2 @16896
//   [33280 + w*7168) wave-w private slab (w=0..5), 7168 B each:
//       h1w bf16 [32][72] @+0 (4608 B; stride 72 keeps ds_read_b128 16B-aligned)
//       h2w bf16 [32][40] @+4608 (2560 B)
//       eo_w f32 [32][33] aliases @+0 after h1w dead (within-wave alias: safe)
//   [76288, 77312) gate f32 [32][8] (waves 6/7 write, mixing reads)
#define SLAB_OFF 33280
#define SLAB_SZ  7168
#define LDS_BYTES 77312

__global__ __launch_bounds__(512, 4) void ple_fused(
    const float* __restrict__ x,
    const unsigned short* __restrict__ wf1, const unsigned short* __restrict__ wf2,
    const unsigned short* __restrict__ wf3,
    const float* __restrict__ b1c, const float* __restrict__ b2c, const float* __restrict__ b3c,
    const float* __restrict__ tw1_W1, const float* __restrict__ tw1_b1,
    const float* __restrict__ tw1_W2, const float* __restrict__ tw1_b2,
    const float* __restrict__ tw2_W1, const float* __restrict__ tw2_b1,
    const float* __restrict__ tw2_W2, const float* __restrict__ tw2_b2,
    float* __restrict__ out, int ntok) {
    extern __shared__ char smem[];
    unsigned short* xlds = (unsigned short*)smem;              // [32][520]
    float* gate = (float*)(smem + 76288);                      // [32][8]
    float* g1l = (float*)smem;                                 // [32][33] (after barrier2)
    float* g2l = (float*)(smem + 4224);                        // [32][33]
    float* th1 = (float*)(smem + 8448);                        // [32][66]
    float* th2 = (float*)(smem + 16896);                       // [32][66]

    const int tid = threadIdx.x;
    const int w = tid >> 6, l = tid & 63, r = l & 15, g = l >> 4;
    const int tok0 = blockIdx.x * MT;

    // ---- phase 1: stage x tile (32 tok x 512) fp32 -> bf16 LDS ----
    {
        const float* xb = x + (size_t)tok0 * 512;
        float4 va[8];
#pragma unroll
        for (int i = 0; i < 4; ++i) {
            va[2 * i] = *(const float4*)(xb + i * 4096 + tid * 8);
            va[2 * i + 1] = *(const float4*)(xb + i * 4096 + tid * 8 + 4);
        }
#pragma unroll
        for (int i = 0; i < 4; ++i) {
            int f = i * 4096 + tid * 8;
            int tok = f >> 9, k = f & 511;
            float4 a = va[2 * i], b = va[2 * i + 1];
            *(uint4*)(&xlds[tok * 520 + k]) =
                make_uint4(pk(a.x, a.y), pk(a.z, a.w), pk(b.x, b.y), pk(b.z, b.w));
        }
    }
    __syncthreads();                                            // barrier 1

    // ---- phase 2: per-wave pipelines (no barriers inside) ----
    const bf16x8* wf1v = (const bf16x8*)wf1;
    if (w < 6) {
        const int e = w;
        unsigned short* h1w = (unsigned short*)(smem + SLAB_OFF + w * SLAB_SZ);  // [32][72]
        unsigned short* h2w = (unsigned short*)(smem + SLAB_OFF + w * SLAB_SZ + 4608); // [32][40]
        float* eow = (float*)(smem + SLAB_OFF + w * SLAB_SZ);   // [32][33] (aliases h1w)

        // L1: x[32,512] @ W1_e[512,64] ; nt tiles e*4 .. e*4+3
        f32x4 acc[4][2];
#pragma unroll
        for (int i = 0; i < 4; ++i)
#pragma unroll
            for (int m = 0; m < 2; ++m) acc[i][m] = (f32x4){0.f, 0.f, 0.f, 0.f};

#pragma unroll 4
        for (int ks = 0; ks < 16; ++ks) {
            bf16x8 bfr[4];
#pragma unroll
            for (int i = 0; i < 4; ++i)
                bfr[i] = wf1v[(((e * 4 + i) * 16 + ks) << 6) + l];
            bf16x8 afr[2];
#pragma unroll
            for (int m = 0; m < 2; ++m)
                afr[m] = *(const bf16x8*)&xlds[(m * 16 + r) * 520 + ks * 32 + g * 8];
#pragma unroll
            for (int i = 0; i < 4; ++i)
#pragma unroll
                for (int m = 0; m < 2; ++m)
                    acc[i][m] = __builtin_amdgcn_mfma_f32_16x16x32_bf16(afr[m], bfr[i], acc[i][m], 0, 0, 0);
        }
        // h1 epilogue: bias+relu -> private LDS (bf16)
#pragma unroll
        for (int i = 0; i < 4; ++i)
#pragma unroll
            for (int m = 0; m < 2; ++m)
#pragma unroll
                for (int q = 0; q < 4; ++q) {
                    float v = acc[i][m][q] + b1c[e * 64 + i * 16 + r];
                    h1w[(m * 16 + g * 4 + q) * 72 + i * 16 + r] = f2bf(fmaxf(v, 0.f));
                }

        // L2: h1[32,64] @ W2_e[64,32]
        const bf16x8* wf2v = (const bf16x8*)wf2;
        f32x4 acc2[2][2];
#pragma unroll
        for (int i = 0; i < 2; ++i)
#pragma unroll
            for (int m = 0; m < 2; ++m) acc2[i][m] = (f32x4){0.f, 0.f, 0.f, 0.f};
#pragma unroll
        for (int ks = 0; ks < 2; ++ks) {
            bf16x8 aa[2];
#pragma unroll
            for (int m = 0; m < 2; ++m)
                aa[m] = *(const bf16x8*)&h1w[(m * 16 + r) * 72 + ks * 32 + g * 8];
#pragma unroll
            for (int i = 0; i < 2; ++i) {
                bf16x8 bb = wf2v[(((e * 2 + i) * 2 + ks) << 6) + l];
#pragma unroll
                for (int m = 0; m < 2; ++m)
                    acc2[i][m] = __builtin_amdgcn_mfma_f32_16x16x32_bf16(aa[m], bb, acc2[i][m], 0, 0, 0);
            }
        }
        // h2 epilogue: bias+relu -> private LDS (bf16)
#pragma unroll
        for (int i = 0; i < 2; ++i)
#pragma unroll
            for (int m = 0; m < 2; ++m)
#pragma unroll
                for (int q = 0; q < 4; ++q) {
                    float v = acc2[i][m][q] + b2c[e * 32 + i * 16 + r];
                    h2w[(m * 16 + g * 4 + q) * 40 + i * 16 + r] = f2bf(fmaxf(v, 0.f));
                }

        // L3: h2[32,32] @ W3_e[32,32] (K=32 -> one MFMA per tile)
        const bf16x8* wf3v = (const bf16x8*)wf3;
        f32x4 acc3[2][2];
#pragma unroll
        for (int i = 0; i < 2; ++i)
#pragma unroll
            for (int m = 0; m < 2; ++m) acc3[i][m] = (f32x4){0.f, 0.f, 0.f, 0.f};
        {
            bf16x8 aa[2];
#pragma unroll
            for (int m = 0; m < 2; ++m)
                aa[m] = *(const bf16x8*)&h2w[(m * 16 + r) * 40 + g * 8];
#pragma unroll
            for (int i = 0; i < 2; ++i) {
                bf16x8 bb = wf3v[((e * 2 + i) << 6) + l];
#pragma unroll
                for (int m = 0; m < 2; ++m)
                    acc3[i][m] = __builtin_amdgcn_mfma_f32_16x16x32_bf16(aa[m], bb, acc3[i][m], 0, 0, 0);
            }
        }
        // eo epilogue: +bias -> f32 (aliases h1w, which is dead)
#pragma unroll
        for (int i = 0; i < 2; ++i)
#pragma unroll
            for (int m = 0; m < 2; ++m)
#pragma unroll
                for (int q = 0; q < 4; ++q)
                    eow[(m * 16 + g * 4 + q) * 33 + i * 16 + r] =
                        acc3[i][m][q] + b3c[e * 32 + i * 16 + r];
    } else {
        // gate waves: w=6 -> tokens 0-15 (m=0), w=7 -> tokens 16-31 (m=1)
        const int m = w - 6;
        f32x4 accg = (f32x4){0.f, 0.f, 0.f, 0.f};
#pragma unroll 4
        for (int ks = 0; ks < 16; ++ks) {
            bf16x8 bfr = wf1v[((24 * 16 + ks) << 6) + l];
            bf16x8 afr = *(const bf16x8*)&xlds[(m * 16 + r) * 520 + ks * 32 + g * 8];
            accg = __builtin_amdgcn_mfma_f32_16x16x32_bf16(afr, bfr, accg, 0, 0, 0);
        }
        if (r < 8) {
#pragma unroll
            for (int q = 0; q < 4; ++q)
                gate[(m * 16 + g * 4 + q) * 8 + r] = accg[q] + b1c[384 + r];
        }
    }
    __syncthreads();                                            // barrier 2

    // ---- phase 3: inline gate softmax + gated mixing -> g1l, g2l ----
    {
        int tok = tid >> 4, c0 = (tid & 15) * 2;
        float lg[8];
#pragma unroll
        for (int i = 0; i < 8; ++i) lg[i] = gate[tok * 8 + i];
        float mx1 = fmaxf(fmaxf(lg[0], lg[1]), fmaxf(lg[2], lg[3]));
        float mx2 = fmaxf(fmaxf(lg[4], lg[5]), fmaxf(lg[6], lg[7]));
        float s1[4], s2[4];
        float d1 = 0.f, d2 = 0.f;
#pragma unroll
        for (int i = 0; i < 4; ++i) { s1[i] = __expf(lg[i] - mx1); d1 += s1[i]; }
#pragma unroll
        for (int i = 0; i < 4; ++i) { s2[i] = __expf(lg[4 + i] - mx2); d2 += s2[i]; }
        float inv1 = 1.f / d1, inv2 = 1.f / d2;
#pragma unroll
        for (int i = 0; i < 4; ++i) { s1[i] *= inv1; s2[i] *= inv2; }

#pragma unroll
        for (int c = 0; c < 2; ++c) {
            int cc = c0 + c;
            const float* eo0 = (const float*)(smem + SLAB_OFF + 0 * SLAB_SZ);
            const float* eo1 = (const float*)(smem + SLAB_OFF + 1 * SLAB_SZ);
            const float* eo2 = (const float*)(smem + SLAB_OFF + 2 * SLAB_SZ);
            const float* eo3 = (const float*)(smem + SLAB_OFF + 3 * SLAB_SZ);
            const float* eo4 = (const float*)(smem + SLAB_OFF + 4 * SLAB_SZ);
            const float* eo5 = (const float*)(smem + SLAB_OFF + 5 * SLAB_SZ);
            float v0 = eo0[tok * 33 + cc], v1 = eo1[tok * 33 + cc];
            float v2 = eo2[tok * 33 + cc], v3 = eo3[tok * 33 + cc];
            float v4 = eo4[tok * 33 + cc], v5 = eo5[tok * 33 + cc];
            // task1 mix: [t1_0, t1_1, sh_0, sh_1]; task2: [t2_0, t2_1, sh_0, sh_1]
            g1l[tok * 33 + cc] = s1[0] * v0 + s1[1] * v1 + s1[2] * v4 + s1[3] * v5;
            g2l[tok * 33 + cc] = s2[0] * v2 + s2[1] * v3 + s2[2] * v4 + s2[3] * v5;
        }
    }
    __syncthreads();                                            // barrier 3

    // ---- phase 4: tower hidden (thr 0-255: tower1, 256-511: tower2) ----
    {
        int tt = tid & 255, tower = tid >> 8;
        int tok = tt >> 3, h0 = (tt & 7) * 8;
        const float* W1 = tower ? tw2_W1 : tw1_W1;
        const float* B1 = tower ? tw2_b1 : tw1_b1;
        const float* gl = tower ? g2l : g1l;
        float* th = tower ? th2 : th1;
        float a[8];
#pragma unroll
        for (int hh = 0; hh < 8; ++hh) a[hh] = B1[h0 + hh];
        for (int c = 0; c < 32; ++c) {
            float gv = gl[tok * 33 + c];
#pragma unroll
            for (int hh = 0; hh < 8; ++hh)
                a[hh] += gv * W1[c * 64 + h0 + hh];
        }
#pragma unroll
        for (int hh = 0; hh < 8; ++hh)
            th[tok * 66 + h0 + hh] = fmaxf(a[hh], 0.f);
    }
    __syncthreads();                                            // barrier 4

    // ---- phase 5: tower outputs ----
    if (tid < 128) {
        int tok = tid >> 2, jx = tid & 3;
        if (jx < 3) {
            float s = tw1_b2[jx];
            for (int hh = 0; hh < 64; ++hh) s += th1[tok * 66 + hh] * tw1_W2[hh * 3 + jx];
            if (jx != 1) s = 1.f / (1.f + __expf(-s));           // sigmoid cols 0,2
            out[(size_t)(tok0 + tok) * 3 + jx] = s;
        }
    } else if (tid >= 256 && tid < 384) {
        int t2 = tid - 256, tok = t2 >> 2, jx = t2 & 3;
        if (jx < 2) {
            float s = tw2_b2[jx];
            for (int hh = 0; hh < 64; ++hh) s += th2[tok * 66 + hh] * tw2_W2[hh * 2 + jx];
            if (jx == 1) s = 1.f / (1.f + __expf(-s));           // sigmoid col 1
            out[(size_t)ntok * 3 + (size_t)(tok0 + tok) * 2 + jx] = s;
        }
    }
}

// ---------------- launcher ----------------
extern "C" void kernel_launch(void* const* d_in, const int* in_sizes, int n_in,
                              void* d_out, int out_size, void* d_ws, size_t ws_size,
                              hipStream_t stream) {
    const float* x = (const float*)d_in[0];
    const float* sh_W1 = (const float*)d_in[1];
    const float* sh_b1 = (const float*)d_in[2];
    const float* sh_W2 = (const float*)d_in[3];
    const float* sh_b2 = (const float*)d_in[4];
    const float* sh_W3 = (const float*)d_in[5];
    const float* sh_b3 = (const float*)d_in[6];
    const float* t1_W1 = (const float*)d_in[7];
    const float* t1_b1 = (const float*)d_in[8];
    const float* t1_W2 = (const float*)d_in[9];
    const float* t1_b2 = (const float*)d_in[10];
    const float* t1_W3 = (const float*)d_in[11];
    const float* t1_b3 = (const float*)d_in[12];
    const float* t2_W1 = (const float*)d_in[13];
    const float* t2_b1 = (const float*)d_in[14];
    const float* t2_W2 = (const float*)d_in[15];
    const float* t2_b2 = (const float*)d_in[16];
    const float* t2_W3 = (const float*)d_in[17];
    const float* t2_b3 = (const float*)d_in[18];
    const float* g1_W = (const float*)d_in[19];
    const float* g1_b = (const float*)d_in[20];
    const float* g2_W = (const float*)d_in[21];
    const float* g2_b = (const float*)d_in[22];
    const float* tw1_W1 = (const float*)d_in[23];
    const float* tw1_b1 = (const float*)d_in[24];
    const float* tw1_W2 = (const float*)d_in[25];
    const float* tw1_b2 = (const float*)d_in[26];
    const float* tw2_W1 = (const float*)d_in[27];
    const float* tw2_b1 = (const float*)d_in[28];
    const float* tw2_W2 = (const float*)d_in[29];
    const float* tw2_b2 = (const float*)d_in[30];

    // d_ws layout (bytes): wf1@0 (409600), wf2@409600 (24576), wf3@434176 (12288),
    //                      b1c@446464 (1568), b2c@448032 (768), b3c@448800 (768)
    unsigned short* wf1 = (unsigned short*)d_ws;
    unsigned short* wf2 = (unsigned short*)((char*)d_ws + 409600);
    unsigned short* wf3 = (unsigned short*)((char*)d_ws + 434176);
    float* b1c = (float*)((char*)d_ws + 446464);
    float* b2c = (float*)((char*)d_ws + 448032);
    float* b3c = (float*)((char*)d_ws + 448800);

    pack_all<<<438, 512, 0, stream>>>(sh_W1, t1_W1, t2_W1, g1_W, g2_W,
                                      sh_W2, t1_W2, t2_W2, sh_W3, t1_W3, t2_W3,
                                      sh_b1, t1_b1, t2_b1, sh_b2, t1_b2, t2_b2,
                                      sh_b3, t1_b3, t2_b3, g1_b, g2_b,
                                      wf1, wf2, wf3, b1c, b2c, b3c);

    (void)hipFuncSetAttribute((const void*)ple_fused,
                              hipFuncAttributeMaxDynamicSharedMemorySize, LDS_BYTES);

    int ntok = in_sizes[0] / 512;
    int nblk = ntok / MT;
    ple_fused<<<nblk, 512, LDS_BYTES, stream>>>(
        x, wf1, wf2, wf3, b1c, b2c, b3c,
        tw1_W1, tw1_b1, tw1_W2, tw1_b2, tw2_W1, tw2_b1, tw2_W2, tw2_b2,
        (float*)d_out, ntok);
}